// Round 10
// baseline (91.859 us; speedup 1.0000x reference)
//
#include <hip/hip_runtime.h>
#include <stdint.h>

#define NQ 12
#define DIM 4096
#define NLAYERS 6
#define TPB 256

typedef float v2f __attribute__((ext_vector_type(2)));

// ---------------------------------------------------------------------------
// R10: R9's verified algebra (16 amps/thread, pack bit = k bit 3, 72 gates as
// element-wise pk-fma, passes rebase/S1/S2/S3 per layer) with two changes:
//  1. ROLLED layer loop (code ~12 KB, fits 32 KB L1I, reused 6x). R9 streamed
//     ~54 KB of straight-line code from L2 every wave (FETCH_SIZE ~ 8 XCDs x
//     code size) -> instruction-fetch bound.
//  2. S1/S2 are WAVE-LOCAL passes: their maps touch only k bits 0..8 (local +
//     lane); Lambda10 keeps slot bits 10,11 = k bits 10,11 (wave id), so each
//     wave exchanges inside its private 1024-slot region with only
//     s_waitcnt lgkmcnt(0) — no __syncthreads. Barriers 23 -> 17.
// Buffers: bufB only for rebase (write;bar;read). bufA for S1/S2 (wave chunks)
// and S3 (pre-bar;write;bar;read). Ordering proof: rebase's barrier orders all
// prior S3-reads(A) before S1-writes(A); S3's pre-barrier orders S2-reads(A)
// and prior rebase-reads(B) before the next writes.
// ---------------------------------------------------------------------------
struct Pass_t {
    uint32_t WT[8];    // Lambda cols, k bits 4..11
    uint32_t WL[8];    // Lambda(j), local bits 0..2
    uint32_t RT[8];    // (Lambda o M) cols, k bits 4..11
    uint32_t RL[16];   // (Lambda o M)(l), local bits 0..3
    bool r64;
};
struct Pass10_t {      // wave-local: 10-bit space (k bits 0..9)
    uint32_t WT[6];
    uint32_t WL[8];
    uint32_t RT[6];
    uint32_t RL[16];
    bool r64;
};
struct CK_t {
    Pass10_t PS1, PS2;     // wave-local window swaps
    Pass_t PS3;            // cross-wave window swap
    Pass_t P1[NLAYERS];    // per-layer rebase (index 1..5 used)
    uint32_t frow[NQ];     // epilogue sign rows
};

constexpr uint32_t S1f(uint32_t k){ return ((k&7u)<<3) | ((k>>3)&7u) | (k & 0xFC0u); }
constexpr uint32_t S2f(uint32_t k){ return ((k&7u)<<6) | (k & 0x38u) | ((k>>6)&7u) | (k & 0xE00u); }
constexpr uint32_t S3f(uint32_t k){ return ((k&7u)<<9) | (k & 0x1F8u) | ((k>>9)&7u); }

constexpr uint32_t ech_reduce(const uint32_t* v, int n, uint32_t x){
    bool ch = true;
    while (ch) {
        ch = false;
        for (int i = 0; i < n; i++)
            if (v[i] && (x ^ v[i]) < x) { x ^= v[i]; ch = true; }
    }
    return x;
}

constexpr Pass_t build_pass(const uint32_t* Mc) {
    Pass_t P{};
    bool r64 = (Mc[3] == 8u);
    for (int j = 0; j < 12; j++) if (j != 3 && (Mc[j] & 8u)) r64 = false;
    P.r64 = r64;
    uint32_t rows[12]{};
    rows[0] = 8u;
    int nr = 1;
    uint32_t full[12]{}; int nf = 0; full[nf++] = 8u;
    uint32_t We[4]{};  int nw = 0;
    uint32_t Re[5]{};  int nre = 0;
    const int rpn = r64 ? 4 : 5;
    if (!r64) {
        uint32_t p0 = 0;
        for (int j = 0; j < rpn; j++)
            p0 |= (uint32_t)(__builtin_popcount(8u & Mc[4 + j]) & 1) << j;
        uint32_t r = ech_reduce(Re, nre, p0);
        if (r) Re[nre++] = r;
    }
    for (int slot = 0; slot < 4; slot++) {
        uint32_t chosen = 0;
        for (int relax = 0; relax < 3 && !chosen; relax++) {
            for (uint32_t m = 1; m < 4096u && !chosen; m++) {
                if (m & 8u) continue;
                uint32_t wp = (m >> 4) & 15u;
                uint32_t wr = ech_reduce(We, nw, wp);
                if (relax < 2 && !wr) continue;
                uint32_t rp = 0;
                for (int j = 0; j < rpn; j++)
                    rp |= (uint32_t)(__builtin_popcount(m & Mc[4 + j]) & 1) << j;
                uint32_t rr = ech_reduce(Re, nre, rp);
                if (relax < 1 && !rr) continue;
                uint32_t fr = ech_reduce(full, nf, m);
                if (!fr) continue;
                chosen = m; full[nf++] = fr;
                if (wr && nw < 4) We[nw++] = wr;
                if (rr && nre < 5) Re[nre++] = rr;
            }
        }
        rows[nr++] = chosen;
    }
    for (int slot = nr; slot < 12; slot++) {
        for (uint32_t m = 1; m < 4096u; m++) {
            if (m & 8u) continue;
            uint32_t fr = ech_reduce(full, nf, m);
            if (fr) { rows[slot] = m; full[nf++] = fr; break; }
        }
    }
    uint32_t col[12]{}, lmc[12]{};
    for (int j = 0; j < 12; j++) {
        uint32_t c = 0;
        for (int i = 0; i < 12; i++) c |= (uint32_t)((rows[i] >> j) & 1u) << i;
        col[j] = c;
    }
    for (int j = 0; j < 12; j++) {
        uint32_t a = 0, mc = Mc[j];
        for (int q = 0; q < 12; q++) if ((mc >> q) & 1u) a ^= col[q];
        lmc[j] = a;
    }
    for (int j = 0; j < 8; j++) { P.WT[j] = col[4 + j]; P.RT[j] = lmc[4 + j]; }
    for (int j = 0; j < 8; j++) {
        uint32_t a = 0;
        for (int q = 0; q < 3; q++) if ((j >> q) & 1) a ^= col[q];
        P.WL[j] = a;
    }
    for (int l = 0; l < 16; l++) {
        uint32_t a = 0;
        for (int q = 0; q < 4; q++) if ((l >> q) & 1) a ^= lmc[q];
        P.RL[l] = a;
    }
    return P;
}

constexpr Pass10_t build_pass10(const uint32_t* Mc) {
    Pass10_t P{};
    bool r64 = (Mc[3] == 8u);
    for (int j = 0; j < 10; j++) if (j != 3 && (Mc[j] & 8u)) r64 = false;
    P.r64 = r64;
    uint32_t rows[10]{};
    rows[0] = 8u;
    int nr = 1;
    uint32_t full[10]{}; int nf = 0; full[nf++] = 8u;
    uint32_t We[4]{};  int nw = 0;
    uint32_t Re[5]{};  int nre = 0;
    const int rpn = r64 ? 4 : 5;
    if (!r64) {
        uint32_t p0 = 0;
        for (int j = 0; j < rpn; j++)
            p0 |= (uint32_t)(__builtin_popcount(8u & Mc[4 + j]) & 1) << j;
        uint32_t r = ech_reduce(Re, nre, p0);
        if (r) Re[nre++] = r;
    }
    for (int slot = 0; slot < 4; slot++) {
        uint32_t chosen = 0;
        for (int relax = 0; relax < 3 && !chosen; relax++) {
            for (uint32_t m = 1; m < 1024u && !chosen; m++) {
                if (m & 8u) continue;
                uint32_t wp = (m >> 4) & 15u;
                uint32_t wr = ech_reduce(We, nw, wp);
                if (relax < 2 && !wr) continue;
                uint32_t rp = 0;
                for (int j = 0; j < rpn; j++)
                    rp |= (uint32_t)(__builtin_popcount(m & Mc[4 + j]) & 1) << j;
                uint32_t rr = ech_reduce(Re, nre, rp);
                if (relax < 1 && !rr) continue;
                uint32_t fr = ech_reduce(full, nf, m);
                if (!fr) continue;
                chosen = m; full[nf++] = fr;
                if (wr && nw < 4) We[nw++] = wr;
                if (rr && nre < 5) Re[nre++] = rr;
            }
        }
        rows[nr++] = chosen;
    }
    for (int slot = nr; slot < 10; slot++) {
        for (uint32_t m = 1; m < 1024u; m++) {
            if (m & 8u) continue;
            uint32_t fr = ech_reduce(full, nf, m);
            if (fr) { rows[slot] = m; full[nf++] = fr; break; }
        }
    }
    uint32_t col[10]{}, lmc[10]{};
    for (int j = 0; j < 10; j++) {
        uint32_t c = 0;
        for (int i = 0; i < 10; i++) c |= (uint32_t)((rows[i] >> j) & 1u) << i;
        col[j] = c;
    }
    for (int j = 0; j < 10; j++) {
        uint32_t a = 0, mc = Mc[j];
        for (int q = 0; q < 10; q++) if ((mc >> q) & 1u) a ^= col[q];
        lmc[j] = a;
    }
    for (int j = 0; j < 6; j++) { P.WT[j] = col[4 + j]; P.RT[j] = lmc[4 + j]; }
    for (int j = 0; j < 8; j++) {
        uint32_t a = 0;
        for (int q = 0; q < 3; q++) if ((j >> q) & 1) a ^= col[q];
        P.WL[j] = a;
    }
    for (int l = 0; l < 16; l++) {
        uint32_t a = 0;
        for (int q = 0; q < 4; q++) if ((l >> q) & 1) a ^= lmc[q];
        P.RL[l] = a;
    }
    return P;
}

constexpr CK_t build_ck() {
    CK_t ck{};
    uint32_t Acols[NLAYERS][NQ]{}, Aicol5[NQ]{};
    for (int l = 0; l < NLAYERS; l++) {
        int r = l % (NQ - 1) + 1;
        for (int q = 0; q < NQ; q++) {
            uint32_t v = 1u << q;
            for (int w = NQ - 1; w >= 0; w--) {            // A = T0∘T1∘...∘T11
                int pc = NQ - 1 - w, pt = NQ - 1 - ((w + r) % NQ);
                v ^= ((v >> pc) & 1u) << pt;
            }
            Acols[l][q] = v;
            if (l == NLAYERS - 1) {
                uint32_t u = 1u << q;
                for (int w = 0; w < NQ; w++) {             // A^-1
                    int pc = NQ - 1 - w, pt = NQ - 1 - ((w + r) % NQ);
                    u ^= ((u >> pc) & 1u) << pt;
                }
                Aicol5[q] = u;
            }
        }
    }
    uint32_t Mc10[10]{};
    for (int j = 0; j < 10; j++) Mc10[j] = S1f(1u << j);
    ck.PS1 = build_pass10(Mc10);
    for (int j = 0; j < 10; j++) Mc10[j] = S2f(1u << j);
    ck.PS2 = build_pass10(Mc10);
    uint32_t Mc[12]{};
    for (int j = 0; j < 12; j++) Mc[j] = S3f(1u << j);
    ck.PS3 = build_pass(Mc);
    for (int l = 1; l < NLAYERS; l++) {
        for (int j = 0; j < 12; j++) Mc[j] = S3f(S2f(S1f(Acols[l - 1][j])));
        ck.P1[l] = build_pass(Mc);
    }
    uint32_t Mcol[NQ]{};
    for (int j = 0; j < NQ; j++) {
        uint32_t pj = S1f(S2f(S3f(1u << j)));
        uint32_t M = 0;
        for (int m = 0; m < NQ; m++) if ((pj >> m) & 1u) M ^= Aicol5[m];
        Mcol[j] = M;
    }
    for (int p = 0; p < NQ; p++) {
        uint32_t s = 0;
        for (int j = 0; j < NQ; j++) s |= ((Mcol[j] >> p) & 1u) << j;
        ck.frow[p] = s;
    }
    return ck;
}
constexpr CK_t CK = build_ck();
static_assert(CK.PS2.r64, "S2 must fix the pack bit (b64 reads)");
static_assert(CK.PS3.r64, "S3 must fix the pack bit (b64 reads)");

// rotation at local bit Q; m = (m00r,m00i,m01r,m01i); element-wise pk math.
template<int Q>
__device__ __forceinline__ void gate_q(v2f (&PRE)[8], v2f (&PIM)[8], float4 m) {
    v2f bx = {m.x, m.x}, by = {m.y, m.y}, bz = {m.z, m.z}, bw = {m.w, m.w};
    #pragma unroll
    for (int j = 0; j < 8; j++) {
        if (j & (1 << Q)) continue;
        int j2 = j | (1 << Q);
        v2f re0 = PRE[j], im0 = PIM[j], re1 = PRE[j2], im1 = PIM[j2];
        PRE[j]  = __builtin_elementwise_fma(bx, re0,
                  __builtin_elementwise_fma(by, -im0,
                  __builtin_elementwise_fma(bz, re1, -bw * im1)));
        PIM[j]  = __builtin_elementwise_fma(bx, im0,
                  __builtin_elementwise_fma(by, re0,
                  __builtin_elementwise_fma(bz, im1, bw * re1)));
        PRE[j2] = __builtin_elementwise_fma(bx, re1,
                  __builtin_elementwise_fma(by, im1,
                  __builtin_elementwise_fma(bz, -re0, -bw * im0)));
        PIM[j2] = __builtin_elementwise_fma(bx, im1,
                  __builtin_elementwise_fma(by, -re1,
                  __builtin_elementwise_fma(bz, -im0, bw * re0)));
    }
}

__device__ __forceinline__ void gate3(v2f (&PRE)[8], v2f (&PIM)[8],
                                      float4 g0, float4 g1, float4 g2) {
    gate_q<0>(PRE, PIM, g0);
    gate_q<1>(PRE, PIM, g1);
    gate_q<2>(PRE, PIM, g2);
}

// wave-local S1 (b32 gather reads), no barrier — same-wave LDS exchange
__device__ __forceinline__ void s1_pass(v2f (&PRE)[8], v2f (&PIM)[8],
                                        float* buf, uint32_t wb, uint32_t rb) {
    constexpr Pass10_t P = CK.PS1;
    v2f* bre = (v2f*)buf;
    v2f* bim = (v2f*)(buf + DIM);
    #pragma unroll
    for (int j = 0; j < 8; j++) {
        uint32_t s = (wb ^ P.WL[j]) >> 1;
        bre[s] = PRE[j]; bim[s] = PIM[j];
    }
    __asm__ volatile("s_waitcnt lgkmcnt(0)" ::: "memory");
    #pragma unroll
    for (int j = 0; j < 8; j++) {
        uint32_t s0 = rb ^ P.RL[j], s1 = rb ^ P.RL[j | 8];
        v2f re, im;
        re.x = buf[s0];       re.y = buf[s1];
        im.x = buf[DIM + s0]; im.y = buf[DIM + s1];
        PRE[j] = re; PIM[j] = im;
    }
}

// wave-local S2 (b64 reads), no barrier
__device__ __forceinline__ void s2_pass(v2f (&PRE)[8], v2f (&PIM)[8],
                                        float* buf, uint32_t wb, uint32_t rb) {
    constexpr Pass10_t P = CK.PS2;
    v2f* bre = (v2f*)buf;
    v2f* bim = (v2f*)(buf + DIM);
    #pragma unroll
    for (int j = 0; j < 8; j++) {
        uint32_t s = (wb ^ P.WL[j]) >> 1;
        bre[s] = PRE[j]; bim[s] = PIM[j];
    }
    __asm__ volatile("s_waitcnt lgkmcnt(0)" ::: "memory");
    #pragma unroll
    for (int j = 0; j < 8; j++) {
        uint32_t s = (rb ^ P.RL[j]) >> 1;
        PRE[j] = bre[s]; PIM[j] = bim[s];
    }
}

// cross-wave S3: pre-barrier (drain wave-local reads) + post-barrier
__device__ __forceinline__ void s3_pass(v2f (&PRE)[8], v2f (&PIM)[8],
                                        float* buf, uint32_t wb, uint32_t rb) {
    constexpr Pass_t P = CK.PS3;
    v2f* bre = (v2f*)buf;
    v2f* bim = (v2f*)(buf + DIM);
    __syncthreads();
    #pragma unroll
    for (int j = 0; j < 8; j++) {
        uint32_t s = (wb ^ P.WL[j]) >> 1;
        bre[s] = PRE[j]; bim[s] = PIM[j];
    }
    __syncthreads();
    #pragma unroll
    for (int j = 0; j < 8; j++) {
        uint32_t s = (rb ^ P.RL[j]) >> 1;
        PRE[j] = bre[s]; PIM[j] = bim[s];
    }
}

// cross-wave rebase, runtime layer index (tables via uniform s_loads)
__device__ __forceinline__ void rebase_pass(v2f (&PRE)[8], v2f (&PIM)[8],
                                            float* buf, int tid, int l) {
    const Pass_t& P = CK.P1[l];
    uint32_t wb = 0, rb = 0;
    #pragma unroll
    for (int j = 0; j < 8; j++) {
        uint32_t sel = (uint32_t)(-(int)((tid >> j) & 1));
        wb ^= sel & P.WT[j];
        rb ^= sel & P.RT[j];
    }
    v2f* bre = (v2f*)buf;
    v2f* bim = (v2f*)(buf + DIM);
    #pragma unroll
    for (int j = 0; j < 8; j++) {
        uint32_t s = (wb ^ P.WL[j]) >> 1;
        bre[s] = PRE[j]; bim[s] = PIM[j];
    }
    __syncthreads();
    #pragma unroll
    for (int j = 0; j < 8; j++) {
        uint32_t s0 = rb ^ P.RL[j], s1 = rb ^ P.RL[j | 8];
        v2f re, im;
        re.x = buf[s0];       re.y = buf[s1];
        im.x = buf[DIM + s0]; im.y = buf[DIM + s1];
        PRE[j] = re; PIM[j] = im;
    }
}

__global__ __launch_bounds__(TPB) void qsim_kernel(
    const float* __restrict__ x,        // [512,12]
    const float* __restrict__ weights,  // [6,12,3]
    const float* __restrict__ Wp,       // [12]
    const float* __restrict__ bptr,     // [1]
    float* __restrict__ out)            // [512]
{
    __shared__ float  lds[2 * 2 * DIM]; // bufA [0,8192), bufB [8192,16384)
    __shared__ float4 smat[NLAYERS * NQ];
    __shared__ float  scs[NQ], sss[NQ];
    __shared__ float  red[4];

    const int tid = threadIdx.x;
    const int b   = blockIdx.x;

    if (tid < NQ) {
        float s_, c_;
        sincosf(0.5f * x[b * NQ + tid], &s_, &c_);
        scs[tid] = c_; sss[tid] = s_;
    }
    if (tid < NLAYERS * NQ) {
        float phi   = weights[tid * 3 + 0];
        float theta = weights[tid * 3 + 1];
        float omega = weights[tid * 3 + 2];
        float st, ct; sincosf(0.5f * theta, &st, &ct);
        float sp, cp; sincosf(0.5f * (phi + omega), &sp, &cp);
        float sm, cm; sincosf(0.5f * (phi - omega), &sm, &cm);
        smat[tid] = make_float4(cp * ct, -sp * ct, -cm * st, -sm * st);
    }
    __syncthreads();

    // init, identity basis: k = (tid<<4)|l; local bits 0..2 <-> wires 11,10,9;
    // pack bit 3 <-> wire 8; tid bit j <-> wire 7-j.
    float base = 1.0f;
    #pragma unroll
    for (int j = 0; j < 8; j++) {
        int w = 7 - j;
        base *= ((tid >> j) & 1) ? sss[w] : scs[w];
    }
    v2f PRE[8], PIM[8];
    float c8 = scs[8], s8 = sss[8];
    #pragma unroll
    for (int j = 0; j < 8; j++) {
        float a = base;
        #pragma unroll
        for (int p = 0; p < 3; p++) {
            int w = NQ - 1 - p;
            a *= ((j >> p) & 1) ? sss[w] : scs[w];
        }
        PRE[j].x = a * c8;  PRE[j].y = a * s8;
        PIM[j].x = 0.0f;    PIM[j].y = 0.0f;
    }

    // precompute fixed-pass bases (S1/S2 include wave-region offset)
    uint32_t s1wb = 0, s1rb = 0, s2wb = 0, s2rb = 0, s3wb = 0, s3rb = 0;
    {
        constexpr Pass10_t Q1 = CK.PS1;
        constexpr Pass10_t Q2 = CK.PS2;
        constexpr Pass_t   Q3 = CK.PS3;
        #pragma unroll
        for (int j = 0; j < 6; j++) {
            uint32_t sel = (uint32_t)(-(int)((tid >> j) & 1));
            s1wb ^= sel & Q1.WT[j]; s1rb ^= sel & Q1.RT[j];
            s2wb ^= sel & Q2.WT[j]; s2rb ^= sel & Q2.RT[j];
        }
        #pragma unroll
        for (int j = 0; j < 8; j++) {
            uint32_t sel = (uint32_t)(-(int)((tid >> j) & 1));
            s3wb ^= sel & Q3.WT[j]; s3rb ^= sel & Q3.RT[j];
        }
        uint32_t wvb = (uint32_t)(tid & 0xC0) << 4;   // wave id -> slot bits 10,11
        s1wb |= wvb; s1rb |= wvb; s2wb |= wvb; s2rb |= wvb;
    }

    float* bufA = lds;
    float* bufB = lds + 2 * DIM;

    #pragma clang loop unroll(disable)
    for (int l = 0; l < NLAYERS; l++) {
        if (l > 0) rebase_pass(PRE, PIM, bufB, tid, l);
        const int sb = l * NQ;
        gate3(PRE, PIM, smat[sb + 11], smat[sb + 10], smat[sb + 9]);
        s1_pass(PRE, PIM, bufA, s1wb, s1rb);
        gate3(PRE, PIM, smat[sb + 8], smat[sb + 7], smat[sb + 6]);
        s2_pass(PRE, PIM, bufA, s2wb, s2rb);
        gate3(PRE, PIM, smat[sb + 5], smat[sb + 4], smat[sb + 3]);
        s3_pass(PRE, PIM, bufA, s3wb, s3rb);
        gate3(PRE, PIM, smat[sb + 2], smat[sb + 1], smat[sb + 0]);
    }

    // expectation: coef = b + sum_p W[11-p]*(1-2*bit_p(i(k))), packed halves
    const float bv = bptr[0];
    float wbT[NQ];
    #pragma unroll
    for (int p = 0; p < NQ; p++) {
        uint32_t row = CK.frow[p];
        int tp = __popc(tid & (int)(row >> 4)) & 1;
        float Wv = Wp[NQ - 1 - p];
        wbT[p] = tp ? -Wv : Wv;
    }
    v2f acc2 = {0.0f, 0.0f};
    #pragma unroll
    for (int j = 0; j < 8; j++) {
        float cx = bv, cy = bv;
        #pragma unroll
        for (int p = 0; p < NQ; p++) {
            uint32_t row = CK.frow[p];
            float s = (__popc(j & (int)(row & 7u)) & 1) ? -wbT[p] : wbT[p];
            cx += s;
            cy += (row & 8u) ? -s : s;
        }
        v2f c = {cx, cy};
        acc2 += (PRE[j] * PRE[j] + PIM[j] * PIM[j]) * c;
    }
    float acc = acc2.x + acc2.y;
    #pragma unroll
    for (int off = 32; off > 0; off >>= 1)
        acc += __shfl_down(acc, off, 64);
    if ((tid & 63) == 0) red[tid >> 6] = acc;
    __syncthreads();
    if (tid == 0) out[b] = red[0] + red[1] + red[2] + red[3];
}

extern "C" void kernel_launch(void* const* d_in, const int* in_sizes, int n_in,
                              void* d_out, int out_size, void* d_ws, size_t ws_size,
                              hipStream_t stream) {
    const float* x       = (const float*)d_in[0];
    const float* weights = (const float*)d_in[1];
    const float* W       = (const float*)d_in[2];
    const float* bptr    = (const float*)d_in[3];
    qsim_kernel<<<512, TPB, 0, stream>>>(x, weights, W, bptr, (float*)d_out);
}

// Round 11
// 91.050 us; speedup vs baseline: 1.0089x; 1.0089x over previous
//
#include <hip/hip_runtime.h>
#include <stdint.h>

#define NQ 12
#define DIM 4096
#define NLAYERS 6
#define TPB 256

typedef float v2f __attribute__((ext_vector_type(2)));

// ---------------------------------------------------------------------------
// R11: R10's verified circuit algebra with a pack-preserving window schedule:
//   k bits: 0-2 local (gated), 3 pack (v2f lane), 4-9 lane, 10-11 wave.
//   Per layer: [rebase: fold CNOT A_{l-1}] g(w11,w10,w9) packgate(w8)
//              S1(0-2<->4-6, wave-local) g(7,6,5)
//              S2(0-2<->7-9, wave-local) g(4,3,2)
//              S3(0-1<->10-11, cross-wave) g(1,0)
//   S1/S2/S3 fix the pack bit => all their LDS traffic is float4
//   (REpair|IMpair) b128, 8 writes + 8 reads per pass. Only rebase reads are
//   b32 scatter (CNOT mixes the pack bit; unavoidable).
//   Wire 8 (pack-resident) gated in-register via sign-vector pk math.
//   Per-layer gate matrices register-cached (12 float4) to keep LDS
//   broadcasts + their latency out of the gate phases. Rolled layer loop
//   (R10's L1I win). Layouts Lambda per pass: row0 = pack functional (cell
//   h-alignment), rows 1-3 rank-3 on write lane span {e4,e5,e6} and read
//   span {M(e4),M(e5),M(e6)} => conflict-free-ish b128 (<=2-way free).
// ---------------------------------------------------------------------------
struct PB {
    uint32_t WT[8], WL[8];   // Lambda unit cols: tid bits / local combos (even)
    uint32_t RT[8], RL[8];   // (Lambda o M): b128 reads (pack-fixed passes)
    uint32_t BT[8], BL[16];  // rearranged byte cols for b32 reads (rebase)
};
struct CK_t {
    PB PS1, PS2, PS3;
    PB P1[NLAYERS];          // rebase, index 1..5 used
    uint32_t frow[NQ];       // epilogue sign rows
};

constexpr uint32_t S1n(uint32_t k){ return ((k&7u)<<4) | ((k>>4)&7u) | (k & 0xF88u); }
constexpr uint32_t S2n(uint32_t k){ return ((k&7u)<<7) | ((k>>7)&7u) | (k & 0xC78u); }
constexpr uint32_t S3n(uint32_t k){ return ((k&3u)<<10) | ((k>>10)&3u) | (k & 0x3FCu); }
constexpr uint32_t rearr(uint32_t u){ return ((u>>1)<<4) | ((u&1u)<<2); }

constexpr uint32_t ech_reduce(const uint32_t* v, int n, uint32_t x){
    bool ch = true;
    while (ch) {
        ch = false;
        for (int i = 0; i < n; i++)
            if (v[i] && (x ^ v[i]) < x) { x ^= v[i]; ch = true; }
    }
    return x;
}

constexpr PB build_pb(const uint32_t* Mc, int nb) {
    uint32_t rows[12]{}; rows[0] = 8u; int nr = 1;     // row0 = pack functional
    uint32_t full[12]{}; int nf = 0; full[nf++] = 8u;
    uint32_t Wsp[3] = {1u<<4, 1u<<5, 1u<<6};
    uint32_t Rsp[3] = {Mc[4], Mc[5], Mc[6]};
    uint32_t eW[3]{}, eR[3]{}; int nW = 0, nR = 0;
    for (int slot = 0; slot < 3; slot++) {
        uint32_t chosen = 0;
        for (int relax = 0; relax < 3 && !chosen; relax++) {
            for (uint32_t m = 1; m < (1u << nb) && !chosen; m++) {
                if (m & 8u) continue;                   // keep h = unit bit0
                uint32_t wp = 0, rp = 0;
                for (int j = 0; j < 3; j++) {
                    wp |= (uint32_t)(__builtin_popcount(m & Wsp[j]) & 1) << j;
                    rp |= (uint32_t)(__builtin_popcount(m & Rsp[j]) & 1) << j;
                }
                uint32_t wr = ech_reduce(eW, nW, wp);
                if (relax < 2 && !wr) continue;
                uint32_t rr = ech_reduce(eR, nR, rp);
                if (relax < 1 && !rr) continue;
                uint32_t fr = ech_reduce(full, nf, m);
                if (!fr) continue;
                chosen = m; full[nf++] = fr;
                if (wr && nW < 3) eW[nW++] = wr;
                if (rr && nR < 3) eR[nR++] = rr;
            }
        }
        rows[nr++] = chosen;
    }
    for (int s = nr; s < nb; s++) {
        for (uint32_t m = 1; m < (1u << nb); m++) {
            if (m & 8u) continue;
            uint32_t fr = ech_reduce(full, nf, m);
            if (fr) { rows[s] = m; full[nf++] = fr; break; }
        }
    }
    uint32_t col[12]{}, lmc[12]{};
    for (int j = 0; j < 12; j++) {
        if (j < nb) {
            uint32_t c = 0;
            for (int i = 0; i < nb; i++) c |= (uint32_t)((rows[i] >> j) & 1u) << i;
            col[j] = c;
        } else col[j] = 1u << j;                        // passthrough (wave bits)
    }
    for (int j = 0; j < 12; j++) {
        uint32_t a = 0, mc = Mc[j];
        for (int q = 0; q < 12; q++) if ((mc >> q) & 1u) a ^= col[q];
        lmc[j] = a;
    }
    PB P{};
    for (int j = 0; j < 8; j++) {
        P.WT[j] = col[4 + j]; P.RT[j] = lmc[4 + j]; P.BT[j] = rearr(lmc[4 + j]);
    }
    for (int j = 0; j < 8; j++) {
        uint32_t a = 0, b = 0;
        for (int q = 0; q < 3; q++) if ((j >> q) & 1) { a ^= col[q]; b ^= lmc[q]; }
        P.WL[j] = a; P.RL[j] = b;
        P.BL[j] = rearr(b); P.BL[8 + j] = rearr(b ^ lmc[3]);
    }
    return P;
}

constexpr CK_t build_ck() {
    CK_t ck{};
    uint32_t Acols[NLAYERS][NQ]{}, Aicol5[NQ]{};
    for (int l = 0; l < NLAYERS; l++) {
        int r = l % (NQ - 1) + 1;
        for (int q = 0; q < NQ; q++) {
            uint32_t v = 1u << q;
            for (int w = NQ - 1; w >= 0; w--) {            // A = T0∘T1∘...∘T11
                int pc = NQ - 1 - w, pt = NQ - 1 - ((w + r) % NQ);
                v ^= ((v >> pc) & 1u) << pt;
            }
            Acols[l][q] = v;
            if (l == NLAYERS - 1) {
                uint32_t u = 1u << q;
                for (int w = 0; w < NQ; w++) {             // A^-1
                    int pc = NQ - 1 - w, pt = NQ - 1 - ((w + r) % NQ);
                    u ^= ((u >> pc) & 1u) << pt;
                }
                Aicol5[q] = u;
            }
        }
    }
    uint32_t Mc[12]{};
    for (int j = 0; j < 12; j++) Mc[j] = S1n(1u << j);
    ck.PS1 = build_pb(Mc, 10);
    for (int j = 0; j < 12; j++) Mc[j] = S2n(1u << j);
    ck.PS2 = build_pb(Mc, 10);
    for (int j = 0; j < 12; j++) Mc[j] = S3n(1u << j);
    ck.PS3 = build_pb(Mc, 12);
    for (int l = 1; l < NLAYERS; l++) {
        for (int j = 0; j < 12; j++) Mc[j] = S3n(S2n(S1n(Acols[l - 1][j])));
        ck.P1[l] = build_pb(Mc, 12);
    }
    // epilogue: i(k) = A5^-1(pi'(k)), pi'(v) = S1n(S2n(S3n(v)))
    uint32_t Mcol[NQ]{};
    for (int j = 0; j < NQ; j++) {
        uint32_t pj = S1n(S2n(S3n(1u << j)));
        uint32_t M = 0;
        for (int m = 0; m < NQ; m++) if ((pj >> m) & 1u) M ^= Aicol5[m];
        Mcol[j] = M;
    }
    for (int p = 0; p < NQ; p++) {
        uint32_t s = 0;
        for (int j = 0; j < NQ; j++) s |= ((Mcol[j] >> p) & 1u) << j;
        ck.frow[p] = s;
    }
    return ck;
}
constexpr CK_t CK = build_ck();

// rotation at local bit Q; m = (m00r,m00i,m01r,m01i); element-wise pk math.
template<int Q>
__device__ __forceinline__ void gate_q(v2f (&PRE)[8], v2f (&PIM)[8], float4 m) {
    v2f bx = {m.x, m.x}, by = {m.y, m.y}, bz = {m.z, m.z}, bw = {m.w, m.w};
    #pragma unroll
    for (int j = 0; j < 8; j++) {
        if (j & (1 << Q)) continue;
        int j2 = j | (1 << Q);
        v2f re0 = PRE[j], im0 = PIM[j], re1 = PRE[j2], im1 = PIM[j2];
        PRE[j]  = __builtin_elementwise_fma(bx, re0,
                  __builtin_elementwise_fma(by, -im0,
                  __builtin_elementwise_fma(bz, re1, -bw * im1)));
        PIM[j]  = __builtin_elementwise_fma(bx, im0,
                  __builtin_elementwise_fma(by, re0,
                  __builtin_elementwise_fma(bz, im1, bw * re1)));
        PRE[j2] = __builtin_elementwise_fma(bx, re1,
                  __builtin_elementwise_fma(by, im1,
                  __builtin_elementwise_fma(bz, -re0, -bw * im0)));
        PIM[j2] = __builtin_elementwise_fma(bx, im1,
                  __builtin_elementwise_fma(by, -re1,
                  __builtin_elementwise_fma(bz, -im0, bw * re0)));
    }
}

// gate on the pack bit (halves .x/.y of each v2f), sign-vector pk math
__device__ __forceinline__ void pack_gate(v2f (&PRE)[8], v2f (&PIM)[8], float4 m) {
    v2f d1 = {-m.y, m.y}, d2 = {m.z, -m.z};
    #pragma unroll
    for (int j = 0; j < 8; j++) {
        v2f RE = PRE[j], IM = PIM[j];
        v2f sR = {RE.y, RE.x}, sI = {IM.y, IM.x};
        PRE[j] = m.x * RE + d1 * IM + d2 * sR - m.w * sI;
        PIM[j] = m.x * IM - d1 * RE + d2 * sI + m.w * sR;
    }
}

// wave-local pass (S1/S2): float4 cells, no barrier (per-wave DS order + drain)
template<int KIND>
__device__ __forceinline__ void wl_pass(v2f (&PRE)[8], v2f (&PIM)[8],
                                        char* buf, uint32_t wb, uint32_t rb) {
    constexpr PB P = (KIND == 1) ? CK.PS1 : CK.PS2;
    #pragma unroll
    for (int j = 0; j < 8; j++)
        *(float4*)(buf + ((wb ^ P.WL[j]) << 3)) =
            make_float4(PRE[j].x, PRE[j].y, PIM[j].x, PIM[j].y);
    __asm__ volatile("s_waitcnt lgkmcnt(0)" ::: "memory");
    #pragma unroll
    for (int j = 0; j < 8; j++) {
        float4 v = *(const float4*)(buf + ((rb ^ P.RL[j]) << 3));
        PRE[j] = v2f{v.x, v.y}; PIM[j] = v2f{v.z, v.w};
    }
}

// cross-wave window swap S3: pre+post barriers, float4 both ways
__device__ __forceinline__ void s3_pass(v2f (&PRE)[8], v2f (&PIM)[8],
                                        char* buf, uint32_t wb, uint32_t rb) {
    constexpr PB P = CK.PS3;
    __syncthreads();
    #pragma unroll
    for (int j = 0; j < 8; j++)
        *(float4*)(buf + ((wb ^ P.WL[j]) << 3)) =
            make_float4(PRE[j].x, PRE[j].y, PIM[j].x, PIM[j].y);
    __syncthreads();
    #pragma unroll
    for (int j = 0; j < 8; j++) {
        float4 v = *(const float4*)(buf + ((rb ^ P.RL[j]) << 3));
        PRE[j] = v2f{v.x, v.y}; PIM[j] = v2f{v.z, v.w};
    }
}

// cross-wave rebase (folds CNOT): f4 writes, barrier, b32 scatter reads
__device__ __forceinline__ void rebase(v2f (&PRE)[8], v2f (&PIM)[8],
                                       char* buf, int tid, int l) {
    const PB& P = CK.P1[l];
    uint32_t wb = 0, bb = 0;
    #pragma unroll
    for (int j = 0; j < 8; j++) {
        uint32_t sel = (uint32_t)(-(int)((tid >> j) & 1));
        wb ^= sel & P.WT[j];
        bb ^= sel & P.BT[j];
    }
    #pragma unroll
    for (int j = 0; j < 8; j++)
        *(float4*)(buf + ((wb ^ P.WL[j]) << 3)) =
            make_float4(PRE[j].x, PRE[j].y, PIM[j].x, PIM[j].y);
    __syncthreads();
    #pragma unroll
    for (int j = 0; j < 8; j++) {
        const float* p0 = (const float*)(buf + (bb ^ P.BL[j]));
        const float* p1 = (const float*)(buf + (bb ^ P.BL[8 + j]));
        PRE[j] = v2f{p0[0], p1[0]};
        PIM[j] = v2f{p0[2], p1[2]};
    }
}

__global__ __launch_bounds__(TPB) void qsim_kernel(
    const float* __restrict__ x,        // [512,12]
    const float* __restrict__ weights,  // [6,12,3]
    const float* __restrict__ Wp,       // [12]
    const float* __restrict__ bptr,     // [1]
    float* __restrict__ out)            // [512]
{
    __shared__ float4 bufA[DIM / 2];    // 32 KB: S1/S2 (wave regions) + S3
    __shared__ float4 bufB[DIM / 2];    // 32 KB: rebase
    __shared__ float4 smat[NLAYERS * NQ];
    __shared__ float  scs[NQ], sss[NQ];
    __shared__ float  red[4];

    const int tid = threadIdx.x;
    const int b   = blockIdx.x;

    if (tid < NQ) {
        float s_, c_;
        sincosf(0.5f * x[b * NQ + tid], &s_, &c_);
        scs[tid] = c_; sss[tid] = s_;
    }
    if (tid < NLAYERS * NQ) {
        float phi   = weights[tid * 3 + 0];
        float theta = weights[tid * 3 + 1];
        float omega = weights[tid * 3 + 2];
        float st, ct; sincosf(0.5f * theta, &st, &ct);
        float sp, cp; sincosf(0.5f * (phi + omega), &sp, &cp);
        float sm, cm; sincosf(0.5f * (phi - omega), &sm, &cm);
        smat[tid] = make_float4(cp * ct, -sp * ct, -cm * st, -sm * st);
    }
    __syncthreads();

    // init, identity basis: k = (tid<<4)|(h<<3)|j; local bits 0-2 <-> wires
    // 11,10,9; pack bit 3 <-> wire 8; tid bit j <-> wire 7-j.
    float base = 1.0f;
    #pragma unroll
    for (int j = 0; j < 8; j++) {
        int w = 7 - j;
        base *= ((tid >> j) & 1) ? sss[w] : scs[w];
    }
    v2f PRE[8], PIM[8];
    float c8 = scs[8], s8 = sss[8];
    #pragma unroll
    for (int j = 0; j < 8; j++) {
        float a = base;
        #pragma unroll
        for (int p = 0; p < 3; p++) {
            int w = NQ - 1 - p;
            a *= ((j >> p) & 1) ? sss[w] : scs[w];
        }
        PRE[j].x = a * c8;  PRE[j].y = a * s8;
        PIM[j].x = 0.0f;    PIM[j].y = 0.0f;
    }

    // per-pass address bases (wave bits ride along via passthrough columns)
    uint32_t s1wb = 0, s1rb = 0, s2wb = 0, s2rb = 0, s3wb = 0, s3rb = 0;
    #pragma unroll
    for (int j = 0; j < 8; j++) {
        uint32_t sel = (uint32_t)(-(int)((tid >> j) & 1));
        s1wb ^= sel & CK.PS1.WT[j]; s1rb ^= sel & CK.PS1.RT[j];
        s2wb ^= sel & CK.PS2.WT[j]; s2rb ^= sel & CK.PS2.RT[j];
        s3wb ^= sel & CK.PS3.WT[j]; s3rb ^= sel & CK.PS3.RT[j];
    }

    char* bA = (char*)bufA;
    char* bB = (char*)bufB;

    #pragma clang loop unroll(disable)
    for (int l = 0; l < NLAYERS; l++) {
        float4 M[12];
        #pragma unroll
        for (int w = 0; w < 12; w++) M[w] = smat[l * NQ + w];
        if (l > 0) rebase(PRE, PIM, bB, tid, l);
        gate_q<0>(PRE, PIM, M[11]);
        gate_q<1>(PRE, PIM, M[10]);
        gate_q<2>(PRE, PIM, M[9]);
        pack_gate(PRE, PIM, M[8]);
        wl_pass<1>(PRE, PIM, bA, s1wb, s1rb);
        gate_q<0>(PRE, PIM, M[7]);
        gate_q<1>(PRE, PIM, M[6]);
        gate_q<2>(PRE, PIM, M[5]);
        wl_pass<2>(PRE, PIM, bA, s2wb, s2rb);
        gate_q<0>(PRE, PIM, M[4]);
        gate_q<1>(PRE, PIM, M[3]);
        gate_q<2>(PRE, PIM, M[2]);
        s3_pass(PRE, PIM, bA, s3wb, s3rb);
        gate_q<0>(PRE, PIM, M[1]);
        gate_q<1>(PRE, PIM, M[0]);
    }

    // expectation: coef = b + sum_p W[11-p]*(1-2*bit_p(i(k))), packed halves
    const float bv = bptr[0];
    float wbT[NQ];
    #pragma unroll
    for (int p = 0; p < NQ; p++) {
        uint32_t row = CK.frow[p];
        int tp = __popc(tid & (int)(row >> 4)) & 1;
        float Wv = Wp[NQ - 1 - p];
        wbT[p] = tp ? -Wv : Wv;
    }
    v2f acc2 = {0.0f, 0.0f};
    #pragma unroll
    for (int j = 0; j < 8; j++) {
        float cx = bv, cy = bv;
        #pragma unroll
        for (int p = 0; p < NQ; p++) {
            uint32_t row = CK.frow[p];
            float s = (__popc(j & (int)(row & 7u)) & 1) ? -wbT[p] : wbT[p];
            cx += s;
            cy += (row & 8u) ? -s : s;
        }
        v2f c = {cx, cy};
        acc2 += (PRE[j] * PRE[j] + PIM[j] * PIM[j]) * c;
    }
    float acc = acc2.x + acc2.y;
    #pragma unroll
    for (int off = 32; off > 0; off >>= 1)
        acc += __shfl_down(acc, off, 64);
    if ((tid & 63) == 0) red[tid >> 6] = acc;
    __syncthreads();
    if (tid == 0) out[b] = red[0] + red[1] + red[2] + red[3];
}

extern "C" void kernel_launch(void* const* d_in, const int* in_sizes, int n_in,
                              void* d_out, int out_size, void* d_ws, size_t ws_size,
                              hipStream_t stream) {
    const float* x       = (const float*)d_in[0];
    const float* weights = (const float*)d_in[1];
    const float* W       = (const float*)d_in[2];
    const float* bptr    = (const float*)d_in[3];
    qsim_kernel<<<512, TPB, 0, stream>>>(x, weights, W, bptr, (float*)d_out);
}

// Round 12
// 89.263 us; speedup vs baseline: 1.0291x; 1.0200x over previous
//
#include <hip/hip_runtime.h>
#include <stdint.h>

#define NQ 12
#define DIM 4096
#define NLAYERS 6
#define TPB 256

typedef float v2f __attribute__((ext_vector_type(2)));

// ---------------------------------------------------------------------------
// R12: R10's verified machinery, 3 windows of 4 wires per layer (3 local bits
// + the pack bit gated in place) => 17 passes instead of 23.
//   k bits: 0-2 local (gated), 3 pack (v2f lane, gated via pack_gate),
//           4-9 lane (tid 0-5), 10-11 wave (tid 6-7).
//   Layer l: [P_c = rebase: fold CNOT A_{l-1}, cross-wave, 1 barrier]
//            gates w11,w10,w9 + pack w8
//            P_a: swap {0-3}<->{4-7}   (wave-local, lgkmcnt only)
//            gates w7,w6,w5 + pack w4
//            P_b: swap {0-3}<->{8-11}  (cross-wave, pre+post barrier)
//            gates w3,w2,w1 + pack w0
//   Basis algebra (R9 convention, data_new[k] = data_old[M(k)]):
//     Phi after P_a,P_b = M_a.M_b; M_c = (M_a.M_b)^-1 . A = M_b.M_a.A
//     (columns: G2f(G3f(Acols))); epilogue i(k) = A5^-1(G3f(G2f(k))).
//   All passes: 16 b64 writes + 32 b32 scatter reads per thread (pack bit
//   moves in every map). Layouts: row0 = pack functional (b64-pair writes),
//   rows 1-4 greedy rank-4 on write/read lane spans (R10 builder verbatim).
// ---------------------------------------------------------------------------
struct Pass_t {
    uint32_t WT[8];    // Lambda cols, k bits 4..11
    uint32_t WL[8];    // Lambda(j), local bits 0..2
    uint32_t RT[8];    // (Lambda o M) cols, k bits 4..11
    uint32_t RL[16];   // (Lambda o M)(l), local bits 0..3
};
struct Pass10_t {      // wave-local: 10-bit space (k bits 0..9)
    uint32_t WT[6];
    uint32_t WL[8];
    uint32_t RT[6];
    uint32_t RL[16];
};
struct CK_t {
    Pass10_t PA;           // swap {0-3}<->{4-7}, wave-local
    Pass_t PB;             // swap {0-3}<->{8-11}, cross-wave
    Pass_t P1[NLAYERS];    // rebase (index 1..5 used)
    uint32_t frow[NQ];     // epilogue sign rows
};

constexpr uint32_t G2f(uint32_t k){ return ((k&15u)<<8) | (k&0xF0u) | ((k>>8)&15u); }
constexpr uint32_t G3f(uint32_t k){ return ((k&15u)<<4) | ((k>>4)&15u) | (k&0xF00u); }

constexpr uint32_t ech_reduce(const uint32_t* v, int n, uint32_t x){
    bool ch = true;
    while (ch) {
        ch = false;
        for (int i = 0; i < n; i++)
            if (v[i] && (x ^ v[i]) < x) { x ^= v[i]; ch = true; }
    }
    return x;
}

constexpr Pass_t build_pass(const uint32_t* Mc) {
    Pass_t P{};
    uint32_t rows[12]{};
    rows[0] = 8u;                              // row0 = pack functional
    int nr = 1;
    uint32_t full[12]{}; int nf = 0; full[nf++] = 8u;
    uint32_t We[4]{};  int nw = 0;
    uint32_t Re[5]{};  int nre = 0;
    {   // row0's read projection over span Mc[4..8]
        uint32_t p0 = 0;
        for (int j = 0; j < 5; j++)
            p0 |= (uint32_t)(__builtin_popcount(8u & Mc[4 + j]) & 1) << j;
        uint32_t r = ech_reduce(Re, nre, p0);
        if (r) Re[nre++] = r;
    }
    for (int slot = 0; slot < 4; slot++) {
        uint32_t chosen = 0;
        for (int relax = 0; relax < 3 && !chosen; relax++) {
            for (uint32_t m = 1; m < 4096u && !chosen; m++) {
                if (m & 8u) continue;
                uint32_t wp = (m >> 4) & 15u;
                uint32_t wr = ech_reduce(We, nw, wp);
                if (relax < 2 && !wr) continue;
                uint32_t rp = 0;
                for (int j = 0; j < 5; j++)
                    rp |= (uint32_t)(__builtin_popcount(m & Mc[4 + j]) & 1) << j;
                uint32_t rr = ech_reduce(Re, nre, rp);
                if (relax < 1 && !rr) continue;
                uint32_t fr = ech_reduce(full, nf, m);
                if (!fr) continue;
                chosen = m; full[nf++] = fr;
                if (wr && nw < 4) We[nw++] = wr;
                if (rr && nre < 5) Re[nre++] = rr;
            }
        }
        rows[nr++] = chosen;
    }
    for (int slot = nr; slot < 12; slot++) {
        for (uint32_t m = 1; m < 4096u; m++) {
            if (m & 8u) continue;
            uint32_t fr = ech_reduce(full, nf, m);
            if (fr) { rows[slot] = m; full[nf++] = fr; break; }
        }
    }
    uint32_t col[12]{}, lmc[12]{};
    for (int j = 0; j < 12; j++) {
        uint32_t c = 0;
        for (int i = 0; i < 12; i++) c |= (uint32_t)((rows[i] >> j) & 1u) << i;
        col[j] = c;
    }
    for (int j = 0; j < 12; j++) {
        uint32_t a = 0, mc = Mc[j];
        for (int q = 0; q < 12; q++) if ((mc >> q) & 1u) a ^= col[q];
        lmc[j] = a;
    }
    for (int j = 0; j < 8; j++) { P.WT[j] = col[4 + j]; P.RT[j] = lmc[4 + j]; }
    for (int j = 0; j < 8; j++) {
        uint32_t a = 0;
        for (int q = 0; q < 3; q++) if ((j >> q) & 1) a ^= col[q];
        P.WL[j] = a;
    }
    for (int l = 0; l < 16; l++) {
        uint32_t a = 0;
        for (int q = 0; q < 4; q++) if ((l >> q) & 1) a ^= lmc[q];
        P.RL[l] = a;
    }
    return P;
}

constexpr Pass10_t build_pass10(const uint32_t* Mc) {
    Pass10_t P{};
    uint32_t rows[10]{};
    rows[0] = 8u;
    int nr = 1;
    uint32_t full[10]{}; int nf = 0; full[nf++] = 8u;
    uint32_t We[4]{};  int nw = 0;
    uint32_t Re[5]{};  int nre = 0;
    {
        uint32_t p0 = 0;
        for (int j = 0; j < 5; j++)
            p0 |= (uint32_t)(__builtin_popcount(8u & Mc[4 + j]) & 1) << j;
        uint32_t r = ech_reduce(Re, nre, p0);
        if (r) Re[nre++] = r;
    }
    for (int slot = 0; slot < 4; slot++) {
        uint32_t chosen = 0;
        for (int relax = 0; relax < 3 && !chosen; relax++) {
            for (uint32_t m = 1; m < 1024u && !chosen; m++) {
                if (m & 8u) continue;
                uint32_t wp = (m >> 4) & 15u;
                uint32_t wr = ech_reduce(We, nw, wp);
                if (relax < 2 && !wr) continue;
                uint32_t rp = 0;
                for (int j = 0; j < 5; j++)
                    rp |= (uint32_t)(__builtin_popcount(m & Mc[4 + j]) & 1) << j;
                uint32_t rr = ech_reduce(Re, nre, rp);
                if (relax < 1 && !rr) continue;
                uint32_t fr = ech_reduce(full, nf, m);
                if (!fr) continue;
                chosen = m; full[nf++] = fr;
                if (wr && nw < 4) We[nw++] = wr;
                if (rr && nre < 5) Re[nre++] = rr;
            }
        }
        rows[nr++] = chosen;
    }
    for (int slot = nr; slot < 10; slot++) {
        for (uint32_t m = 1; m < 1024u; m++) {
            if (m & 8u) continue;
            uint32_t fr = ech_reduce(full, nf, m);
            if (fr) { rows[slot] = m; full[nf++] = fr; break; }
        }
    }
    uint32_t col[10]{}, lmc[10]{};
    for (int j = 0; j < 10; j++) {
        uint32_t c = 0;
        for (int i = 0; i < 10; i++) c |= (uint32_t)((rows[i] >> j) & 1u) << i;
        col[j] = c;
    }
    for (int j = 0; j < 10; j++) {
        uint32_t a = 0, mc = Mc[j];
        for (int q = 0; q < 10; q++) if ((mc >> q) & 1u) a ^= col[q];
        lmc[j] = a;
    }
    for (int j = 0; j < 6; j++) { P.WT[j] = col[4 + j]; P.RT[j] = lmc[4 + j]; }
    for (int j = 0; j < 8; j++) {
        uint32_t a = 0;
        for (int q = 0; q < 3; q++) if ((j >> q) & 1) a ^= col[q];
        P.WL[j] = a;
    }
    for (int l = 0; l < 16; l++) {
        uint32_t a = 0;
        for (int q = 0; q < 4; q++) if ((l >> q) & 1) a ^= lmc[q];
        P.RL[l] = a;
    }
    return P;
}

constexpr CK_t build_ck() {
    CK_t ck{};
    uint32_t Acols[NLAYERS][NQ]{}, Aicol5[NQ]{};
    for (int l = 0; l < NLAYERS; l++) {
        int r = l % (NQ - 1) + 1;
        for (int q = 0; q < NQ; q++) {
            uint32_t v = 1u << q;
            for (int w = NQ - 1; w >= 0; w--) {            // A = T0∘T1∘...∘T11
                int pc = NQ - 1 - w, pt = NQ - 1 - ((w + r) % NQ);
                v ^= ((v >> pc) & 1u) << pt;
            }
            Acols[l][q] = v;
            if (l == NLAYERS - 1) {
                uint32_t u = 1u << q;
                for (int w = 0; w < NQ; w++) {             // A^-1
                    int pc = NQ - 1 - w, pt = NQ - 1 - ((w + r) % NQ);
                    u ^= ((u >> pc) & 1u) << pt;
                }
                Aicol5[q] = u;
            }
        }
    }
    uint32_t Mc10[10]{};
    for (int j = 0; j < 10; j++) Mc10[j] = G3f(1u << j);      // M_a
    ck.PA = build_pass10(Mc10);
    uint32_t Mc[12]{};
    for (int j = 0; j < 12; j++) Mc[j] = G2f(1u << j);        // M_b
    ck.PB = build_pass(Mc);
    for (int l = 1; l < NLAYERS; l++) {                       // M_c = M_b.M_a.A
        for (int j = 0; j < 12; j++) Mc[j] = G2f(G3f(Acols[l - 1][j]));
        ck.P1[l] = build_pass(Mc);
    }
    // epilogue: i(k) = A5^-1(Phi(k)), Phi = M_a.M_b  (col: G3f(G2f(e_j)))
    uint32_t Mcol[NQ]{};
    for (int j = 0; j < NQ; j++) {
        uint32_t pj = G3f(G2f(1u << j));
        uint32_t M = 0;
        for (int m = 0; m < NQ; m++) if ((pj >> m) & 1u) M ^= Aicol5[m];
        Mcol[j] = M;
    }
    for (int p = 0; p < NQ; p++) {
        uint32_t s = 0;
        for (int j = 0; j < NQ; j++) s |= ((Mcol[j] >> p) & 1u) << j;
        ck.frow[p] = s;
    }
    return ck;
}
constexpr CK_t CK = build_ck();

// rotation at local bit Q; m = (m00r,m00i,m01r,m01i); element-wise pk math.
template<int Q>
__device__ __forceinline__ void gate_q(v2f (&PRE)[8], v2f (&PIM)[8], float4 m) {
    v2f bx = {m.x, m.x}, by = {m.y, m.y}, bz = {m.z, m.z}, bw = {m.w, m.w};
    #pragma unroll
    for (int j = 0; j < 8; j++) {
        if (j & (1 << Q)) continue;
        int j2 = j | (1 << Q);
        v2f re0 = PRE[j], im0 = PIM[j], re1 = PRE[j2], im1 = PIM[j2];
        PRE[j]  = __builtin_elementwise_fma(bx, re0,
                  __builtin_elementwise_fma(by, -im0,
                  __builtin_elementwise_fma(bz, re1, -bw * im1)));
        PIM[j]  = __builtin_elementwise_fma(bx, im0,
                  __builtin_elementwise_fma(by, re0,
                  __builtin_elementwise_fma(bz, im1, bw * re1)));
        PRE[j2] = __builtin_elementwise_fma(bx, re1,
                  __builtin_elementwise_fma(by, im1,
                  __builtin_elementwise_fma(bz, -re0, -bw * im0)));
        PIM[j2] = __builtin_elementwise_fma(bx, im1,
                  __builtin_elementwise_fma(by, -re1,
                  __builtin_elementwise_fma(bz, -im0, bw * re0)));
    }
}

// gate on the pack bit (halves .x/.y of each v2f), sign-vector pk math.
// Verified in R11 (absmax 3.8e-6).
__device__ __forceinline__ void pack_gate(v2f (&PRE)[8], v2f (&PIM)[8], float4 m) {
    v2f d1 = {-m.y, m.y}, d2 = {m.z, -m.z};
    #pragma unroll
    for (int j = 0; j < 8; j++) {
        v2f RE = PRE[j], IM = PIM[j];
        v2f sR = {RE.y, RE.x}, sI = {IM.y, IM.x};
        PRE[j] = m.x * RE + d1 * IM + d2 * sR - m.w * sI;
        PIM[j] = m.x * IM - d1 * RE + d2 * sI + m.w * sR;
    }
}

// wave-local P_a: b64 writes, lgkmcnt drain, b32 scatter reads (R10 s1_pass)
__device__ __forceinline__ void pa_pass(v2f (&PRE)[8], v2f (&PIM)[8],
                                        float* buf, uint32_t wb, uint32_t rb) {
    constexpr Pass10_t P = CK.PA;
    v2f* bre = (v2f*)buf;
    v2f* bim = (v2f*)(buf + DIM);
    #pragma unroll
    for (int j = 0; j < 8; j++) {
        uint32_t s = (wb ^ P.WL[j]) >> 1;
        bre[s] = PRE[j]; bim[s] = PIM[j];
    }
    __asm__ volatile("s_waitcnt lgkmcnt(0)" ::: "memory");
    #pragma unroll
    for (int j = 0; j < 8; j++) {
        uint32_t s0 = rb ^ P.RL[j], s1 = rb ^ P.RL[j | 8];
        v2f re, im;
        re.x = buf[s0];       re.y = buf[s1];
        im.x = buf[DIM + s0]; im.y = buf[DIM + s1];
        PRE[j] = re; PIM[j] = im;
    }
}

// cross-wave P_b: pre-barrier (drain P_a reads block-wide), write, barrier, read
__device__ __forceinline__ void pb_pass(v2f (&PRE)[8], v2f (&PIM)[8],
                                        float* buf, uint32_t wb, uint32_t rb) {
    constexpr Pass_t P = CK.PB;
    v2f* bre = (v2f*)buf;
    v2f* bim = (v2f*)(buf + DIM);
    __syncthreads();
    #pragma unroll
    for (int j = 0; j < 8; j++) {
        uint32_t s = (wb ^ P.WL[j]) >> 1;
        bre[s] = PRE[j]; bim[s] = PIM[j];
    }
    __syncthreads();
    #pragma unroll
    for (int j = 0; j < 8; j++) {
        uint32_t s0 = rb ^ P.RL[j], s1 = rb ^ P.RL[j | 8];
        v2f re, im;
        re.x = buf[s0];       re.y = buf[s1];
        im.x = buf[DIM + s0]; im.y = buf[DIM + s1];
        PRE[j] = re; PIM[j] = im;
    }
}

// cross-wave rebase P_c, runtime layer index (R10 verbatim)
__device__ __forceinline__ void rebase_pass(v2f (&PRE)[8], v2f (&PIM)[8],
                                            float* buf, int tid, int l) {
    const Pass_t& P = CK.P1[l];
    uint32_t wb = 0, rb = 0;
    #pragma unroll
    for (int j = 0; j < 8; j++) {
        uint32_t sel = (uint32_t)(-(int)((tid >> j) & 1));
        wb ^= sel & P.WT[j];
        rb ^= sel & P.RT[j];
    }
    v2f* bre = (v2f*)buf;
    v2f* bim = (v2f*)(buf + DIM);
    #pragma unroll
    for (int j = 0; j < 8; j++) {
        uint32_t s = (wb ^ P.WL[j]) >> 1;
        bre[s] = PRE[j]; bim[s] = PIM[j];
    }
    __syncthreads();
    #pragma unroll
    for (int j = 0; j < 8; j++) {
        uint32_t s0 = rb ^ P.RL[j], s1 = rb ^ P.RL[j | 8];
        v2f re, im;
        re.x = buf[s0];       re.y = buf[s1];
        im.x = buf[DIM + s0]; im.y = buf[DIM + s1];
        PRE[j] = re; PIM[j] = im;
    }
}

__global__ __launch_bounds__(TPB) void qsim_kernel(
    const float* __restrict__ x,        // [512,12]
    const float* __restrict__ weights,  // [6,12,3]
    const float* __restrict__ Wp,       // [12]
    const float* __restrict__ bptr,     // [1]
    float* __restrict__ out)            // [512]
{
    __shared__ float  lds[2 * 2 * DIM]; // bufA [0,8192): P_a/P_b; bufB: rebase
    __shared__ float4 smat[NLAYERS * NQ];
    __shared__ float  scs[NQ], sss[NQ];
    __shared__ float  red[4];

    const int tid = threadIdx.x;
    const int b   = blockIdx.x;

    if (tid < NQ) {
        float s_, c_;
        sincosf(0.5f * x[b * NQ + tid], &s_, &c_);
        scs[tid] = c_; sss[tid] = s_;
    }
    if (tid < NLAYERS * NQ) {
        float phi   = weights[tid * 3 + 0];
        float theta = weights[tid * 3 + 1];
        float omega = weights[tid * 3 + 2];
        float st, ct; sincosf(0.5f * theta, &st, &ct);
        float sp, cp; sincosf(0.5f * (phi + omega), &sp, &cp);
        float sm, cm; sincosf(0.5f * (phi - omega), &sm, &cm);
        smat[tid] = make_float4(cp * ct, -sp * ct, -cm * st, -sm * st);
    }
    __syncthreads();

    // init, identity basis: k = (tid<<4)|(h<<3)|j; local bits 0-2 <-> wires
    // 11,10,9; pack bit 3 <-> wire 8; tid bit j <-> wire 7-j.
    float base = 1.0f;
    #pragma unroll
    for (int j = 0; j < 8; j++) {
        int w = 7 - j;
        base *= ((tid >> j) & 1) ? sss[w] : scs[w];
    }
    v2f PRE[8], PIM[8];
    float c8 = scs[8], s8 = sss[8];
    #pragma unroll
    for (int j = 0; j < 8; j++) {
        float a = base;
        #pragma unroll
        for (int p = 0; p < 3; p++) {
            int w = NQ - 1 - p;
            a *= ((j >> p) & 1) ? sss[w] : scs[w];
        }
        PRE[j].x = a * c8;  PRE[j].y = a * s8;
        PIM[j].x = 0.0f;    PIM[j].y = 0.0f;
    }

    // fixed-pass address bases
    uint32_t pawb = 0, parb = 0, pbwb = 0, pbrb = 0;
    #pragma unroll
    for (int j = 0; j < 6; j++) {
        uint32_t sel = (uint32_t)(-(int)((tid >> j) & 1));
        pawb ^= sel & CK.PA.WT[j]; parb ^= sel & CK.PA.RT[j];
    }
    #pragma unroll
    for (int j = 0; j < 8; j++) {
        uint32_t sel = (uint32_t)(-(int)((tid >> j) & 1));
        pbwb ^= sel & CK.PB.WT[j]; pbrb ^= sel & CK.PB.RT[j];
    }
    {
        uint32_t wvb = (uint32_t)(tid & 0xC0) << 4;   // wave id -> slot bits 10,11
        pawb |= wvb; parb |= wvb;
    }

    float* bufA = lds;
    float* bufB = lds + 2 * DIM;

    #pragma clang loop unroll(disable)
    for (int l = 0; l < NLAYERS; l++) {
        if (l > 0) rebase_pass(PRE, PIM, bufB, tid, l);
        const int sb = l * NQ;
        gate_q<0>(PRE, PIM, smat[sb + 11]);
        gate_q<1>(PRE, PIM, smat[sb + 10]);
        gate_q<2>(PRE, PIM, smat[sb + 9]);
        pack_gate(PRE, PIM, smat[sb + 8]);
        pa_pass(PRE, PIM, bufA, pawb, parb);
        gate_q<0>(PRE, PIM, smat[sb + 7]);
        gate_q<1>(PRE, PIM, smat[sb + 6]);
        gate_q<2>(PRE, PIM, smat[sb + 5]);
        pack_gate(PRE, PIM, smat[sb + 4]);
        pb_pass(PRE, PIM, bufA, pbwb, pbrb);
        gate_q<0>(PRE, PIM, smat[sb + 3]);
        gate_q<1>(PRE, PIM, smat[sb + 2]);
        gate_q<2>(PRE, PIM, smat[sb + 1]);
        pack_gate(PRE, PIM, smat[sb + 0]);
    }

    // expectation: coef = b + sum_p W[11-p]*(1-2*bit_p(i(k))), packed halves
    const float bv = bptr[0];
    float wbT[NQ];
    #pragma unroll
    for (int p = 0; p < NQ; p++) {
        uint32_t row = CK.frow[p];
        int tp = __popc(tid & (int)(row >> 4)) & 1;
        float Wv = Wp[NQ - 1 - p];
        wbT[p] = tp ? -Wv : Wv;
    }
    v2f acc2 = {0.0f, 0.0f};
    #pragma unroll
    for (int j = 0; j < 8; j++) {
        float cx = bv, cy = bv;
        #pragma unroll
        for (int p = 0; p < NQ; p++) {
            uint32_t row = CK.frow[p];
            float s = (__popc(j & (int)(row & 7u)) & 1) ? -wbT[p] : wbT[p];
            cx += s;
            cy += (row & 8u) ? -s : s;
        }
        v2f c = {cx, cy};
        acc2 += (PRE[j] * PRE[j] + PIM[j] * PIM[j]) * c;
    }
    float acc = acc2.x + acc2.y;
    #pragma unroll
    for (int off = 32; off > 0; off >>= 1)
        acc += __shfl_down(acc, off, 64);
    if ((tid & 63) == 0) red[tid >> 6] = acc;
    __syncthreads();
    if (tid == 0) out[b] = red[0] + red[1] + red[2] + red[3];
}

extern "C" void kernel_launch(void* const* d_in, const int* in_sizes, int n_in,
                              void* d_out, int out_size, void* d_ws, size_t ws_size,
                              hipStream_t stream) {
    const float* x       = (const float*)d_in[0];
    const float* weights = (const float*)d_in[1];
    const float* W       = (const float*)d_in[2];
    const float* bptr    = (const float*)d_in[3];
    qsim_kernel<<<512, TPB, 0, stream>>>(x, weights, W, bptr, (float*)d_out);
}